// Round 1
// baseline (230.198 us; speedup 1.0000x reference)
//
#include <hip/hip_runtime.h>

#define CH   288
#define GRPS 32
#define CPG  9
#define IMH  64
#define IMW  64
#define HW   4096
#define NB   8
#define NPX  (NB * HW)     // 32768 total pixel rows
#define BN_EPS 1e-5f

typedef short bf16x8 __attribute__((ext_vector_type(8)));
typedef float f32x4  __attribute__((ext_vector_type(4)));

// ws layout (bytes)
#define XT_OFF   0u            // x_t / tmp_t bf16 [b][p][c]  (18,874,368 B)
#define WIB_OFF  18874368u     // Wi bf16 [288][288]
#define WOS_OFF  19040256u     // Wo*scale bf16 [288][288]
#define S1_OFF   19206144u     // per-channel sum   f32 [288]
#define S2_OFF   19207296u     // per-channel sumsq f32 [288]  (contiguous after s1)
#define SC_OFF   19208448u     // scale f32 [288]
#define SH_OFF   19209600u     // shift f32 [288]
#define BO2_OFF  19210752u     // folded bias f32 [288]

__device__ __forceinline__ unsigned short f2b(float f) {
    unsigned int u = __float_as_uint(f);
    return (unsigned short)((u + 0x7fffu + ((u >> 16) & 1u)) >> 16);
}
__device__ __forceinline__ float b2f(unsigned short h) {
    return __uint_as_float(((unsigned int)h) << 16);
}

// async global->LDS, 16B per lane; dst = wave-uniform base + lane*16
#define GLDS(g, l) __builtin_amdgcn_global_load_lds( \
    (const __attribute__((address_space(1))) void*)(g), \
    (__attribute__((address_space(3))) void*)(l), 16, 0, 0)

__device__ __forceinline__ f32x4 mfma16(bf16x8 a, bf16x8 b, f32x4 c) {
    return __builtin_amdgcn_mfma_f32_16x16x32_bf16(a, b, c, 0, 0, 0);
}

// ---------------------------------------------------------------------------
// K0: x [b][c][p] f32 -> x_t [b][p][c] bf16 (coalesced both sides via LDS)
// ---------------------------------------------------------------------------
#define TS 40
__global__ __launch_bounds__(256) void k_transpose(const float* __restrict__ x,
                                                   unsigned short* __restrict__ xt) {
    __shared__ unsigned short T[64 * TS];
    const int tid = threadIdx.x;
    const int p0 = blockIdx.x * 64;
    const int c0 = blockIdx.y * 32;
    const int b  = blockIdx.z;
    #pragma unroll
    for (int it = 0; it < 2; ++it) {
        const int item  = it * 256 + tid;
        const int c_loc = item >> 4;
        const int p4    = item & 15;
        const float4 v = *(const float4*)(x + (size_t)(b * CH + c0 + c_loc) * HW + p0 + p4 * 4);
        const int px = p4 * 4;
        T[(px + 0) * TS + c_loc] = f2b(v.x);
        T[(px + 1) * TS + c_loc] = f2b(v.y);
        T[(px + 2) * TS + c_loc] = f2b(v.z);
        T[(px + 3) * TS + c_loc] = f2b(v.w);
    }
    __syncthreads();
    const int px_loc = tid >> 2;
    const int cq     = tid & 3;
    const uint4 o = *(const uint4*)((const char*)T + px_loc * (TS * 2) + cq * 16);
    *(uint4*)(xt + ((size_t)b * HW + p0 + px_loc) * CH + c0 + cq * 8) = o;
}

// ---------------------------------------------------------------------------
// K0b: Wi f32 -> bf16
// ---------------------------------------------------------------------------
__global__ __launch_bounds__(256) void k_cvt_wi(const float* __restrict__ Wi,
                                                unsigned short* __restrict__ Wib) {
    const int idx = blockIdx.x * 256 + threadIdx.x;
    const float4 v = ((const float4*)Wi)[idx];
    unsigned short h[4] = {f2b(v.x), f2b(v.y), f2b(v.z), f2b(v.w)};
    *(uint2*)(Wib + (size_t)idx * 4) = *(const uint2*)h;
}

// ---------------------------------------------------------------------------
// K1: LDS-staged MFMA GEMM1 + fused BN stats.
//   tmp_t[px][c] = relu(dot(x_t[px][:], Wi[c][:]) + bi[c])  (bf16, in-place)
// Block: 64 px x 288 c, 4 waves; wave = 32 px x 144 c (2x9 MFMA tiles).
// K-loop LDS rows: 0..63 = x-tile rows, 64..351 = Wi rows (XOR chunk swizzle).
// Epilogue: 2-phase LDS-staged coalesced stores (32 rows x 576 B per phase);
// BN stats via LDS accumulator + one coalesced atomic flush per block.
// ---------------------------------------------------------------------------
__global__ __launch_bounds__(256) void k_gemm1(const unsigned short* __restrict__ Wib,
                                               const float* __restrict__ bi,
                                               unsigned short* __restrict__ xt,
                                               float* __restrict__ s1g) {
    __shared__ unsigned short smem[(64 + 288) * 32];   // 22528 B
    char* smc = (char*)smem;

    const int tid  = threadIdx.x;
    const int wave = tid >> 6;
    const int lane = tid & 63;
    const int q    = lane >> 4;
    const int r    = lane & 15;
    const int pxh  = wave & 1;      // 32-px half
    const int chh  = wave >> 1;     // 144-c half
    const int p0   = blockIdx.x * 64;

    f32x4 acc[2][9];
    #pragma unroll
    for (int t = 0; t < 2; ++t)
        #pragma unroll
        for (int j = 0; j < 9; ++j) acc[t][j] = (f32x4)0.0f;

    const int lrow = lane >> 2;          // staging: row within segment
    const int lp   = lane & 3;           // staging: chunk position

    for (int k0 = 0; k0 < CH; k0 += 32) {
        // ---- stage: 22 segments of 1KB (4 x-tile + 18 Wi-tile) ----
        for (int s = wave; s < 22; s += 4) {
            const int row = s * 16 + lrow;           // LDS row 0..351
            const int sc  = lp ^ ((row >> 1) & 3);   // swizzled source chunk
            const unsigned short* g = (s < 4)
                ? xt  + (size_t)(p0 + row) * CH + k0 + sc * 8
                : Wib + (size_t)(row - 64) * CH + k0 + sc * 8;
            GLDS(g, smc + s * 1024);
        }
        __syncthreads();
        // ---- compute ----
        bf16x8 xf[2];
        #pragma unroll
        for (int t = 0; t < 2; ++t) {
            const int row = pxh * 32 + t * 16 + r;
            xf[t] = *(const bf16x8*)(smc + row * 64 + ((q ^ ((row >> 1) & 3)) * 16));
        }
        #pragma unroll
        for (int j = 0; j < 9; ++j) {
            const int ro = 64 + chh * 144 + j * 16 + r;
            const bf16x8 wf = *(const bf16x8*)(smc + ro * 64 + ((q ^ ((ro >> 1) & 3)) * 16));
            acc[0][j] = mfma16(wf, xf[0], acc[0][j]);
            acc[1][j] = mfma16(wf, xf[1], acc[1][j]);
        }
        __syncthreads();
    }

    // ================= epilogue =================
    // LDS reuse: bytes [0, 18432) = 32-row x 576 B output staging (per phase),
    //            bytes [18432, 20736) = 576-float stats accumulator.
    float* sstat = (float*)(smc + 18432);
    for (int c2 = tid; c2 < 576; c2 += 256) sstat[c2] = 0.0f;
    __syncthreads();

    // ---- BN stats: per-wave shfl reduce over r, LDS atomic accumulate ----
    #pragma unroll 1
    for (int j = 0; j < 9; ++j) {
        const int cb = chh * 144 + j * 16 + q * 4;
        const float4 b4 = *(const float4*)(bi + cb);
        float a1[4] = {0.f, 0.f, 0.f, 0.f}, a2[4] = {0.f, 0.f, 0.f, 0.f};
        #pragma unroll
        for (int t = 0; t < 2; ++t) {
            float v0 = fmaxf(acc[t][j][0] + b4.x, 0.0f);
            float v1 = fmaxf(acc[t][j][1] + b4.y, 0.0f);
            float v2 = fmaxf(acc[t][j][2] + b4.z, 0.0f);
            float v3 = fmaxf(acc[t][j][3] + b4.w, 0.0f);
            a1[0] += v0; a1[1] += v1; a1[2] += v2; a1[3] += v3;
            a2[0] += v0 * v0; a2[1] += v1 * v1; a2[2] += v2 * v2; a2[3] += v3 * v3;
        }
        #pragma unroll
        for (int m = 1; m < 16; m <<= 1) {
            #pragma unroll
            for (int i = 0; i < 4; ++i) {
                a1[i] += __shfl_xor(a1[i], m, 64);
                a2[i] += __shfl_xor(a2[i], m, 64);
            }
        }
        if (r == 0) {
            #pragma unroll
            for (int i = 0; i < 4; ++i) {
                atomicAdd(&sstat[cb + i], a1[i]);
                atomicAdd(&sstat[288 + cb + i], a2[i]);
            }
        }
    }

    // ---- two-phase coalesced store of the 64x288 bf16 tile ----
    #pragma unroll
    for (int ph = 0; ph < 2; ++ph) {
        // stage: this wave's 16-px x 144-c piece for phase ph
        const int lr = pxh * 16 + r;     // local row 0..31
        #pragma unroll
        for (int j = 0; j < 9; ++j) {
            const int cb = chh * 144 + j * 16 + q * 4;
            const float4 b4 = *(const float4*)(bi + cb);
            unsigned short h[4];
            h[0] = f2b(fmaxf(acc[ph][j][0] + b4.x, 0.0f));
            h[1] = f2b(fmaxf(acc[ph][j][1] + b4.y, 0.0f));
            h[2] = f2b(fmaxf(acc[ph][j][2] + b4.z, 0.0f));
            h[3] = f2b(fmaxf(acc[ph][j][3] + b4.w, 0.0f));
            *(uint2*)(smc + lr * 576 + cb * 2) = *(const uint2*)h;
        }
        __syncthreads();
        // cooperative contiguous store: 32 rows x 36 chunks of 16 B
        for (int idx = tid; idx < 1152; idx += 256) {
            const int row = idx / 36;
            const int off = idx - row * 36;
            const int gpx = p0 + ph * 16 + row + (row & 16);
            *(uint4*)(xt + (size_t)gpx * CH + off * 8) =
                *(const uint4*)(smc + row * 576 + off * 16);
        }
        if (ph == 0) {
            // flush stats (s2g is contiguous after s1g in ws)
            for (int c2 = tid; c2 < 576; c2 += 256)
                atomicAdd(&s1g[c2], sstat[c2]);
        }
        __syncthreads();
    }
}

// ---------------------------------------------------------------------------
// K2a: BN scale/shift
// ---------------------------------------------------------------------------
__global__ __launch_bounds__(320) void k_scale(const float* __restrict__ s1,
                                               const float* __restrict__ s2,
                                               const float* __restrict__ gamma,
                                               const float* __restrict__ beta,
                                               float* __restrict__ scale,
                                               float* __restrict__ shift) {
    const int c = threadIdx.x;
    if (c < CH) {
        const float inv = 1.0f / (float)(NB * HW);
        const float mean = s1[c] * inv;
        const float var  = s2[c] * inv - mean * mean;
        const float rs   = rsqrtf(var + BN_EPS);
        const float sc   = gamma[c] * rs;
        scale[c] = sc;
        shift[c] = beta[c] - mean * sc;
    }
}

// ---------------------------------------------------------------------------
// K2b: Wo_s[m][k] = bf16(Wo[m][k]*scale[k]); bo2[m] = bo[m] + Wo[m][:]@shift
// ---------------------------------------------------------------------------
__global__ __launch_bounds__(64) void k_fold(const float* __restrict__ Wo,
                                             const float* __restrict__ bo,
                                             const float* __restrict__ scale,
                                             const float* __restrict__ shift,
                                             unsigned short* __restrict__ Wos,
                                             float* __restrict__ bo2) {
    const int m = blockIdx.x;
    const int t = threadIdx.x;
    float s = 0.0f;
    for (int k = t; k < CH; k += 64) {
        const float wv = Wo[(size_t)m * CH + k];
        s += wv * shift[k];
        Wos[(size_t)m * CH + k] = f2b(wv * scale[k]);
    }
    #pragma unroll
    for (int off = 32; off > 0; off >>= 1) s += __shfl_down(s, off, 64);
    if (t == 0) bo2[m] = bo[m] + s;
}

// ---------------------------------------------------------------------------
// K3: LDS-staged MFMA GEMM2 (ker = Wo_s @ tmp + bo2) -> kerL -> involution.
// Block: 32 px x 288 ker-ch, 4 waves; wave = 16 px x 144 c (9 tiles).
// ---------------------------------------------------------------------------
#define KLS 36
__global__ __launch_bounds__(256) void k_gemm2_invol(const unsigned short* __restrict__ xt,
                                                     const unsigned short* __restrict__ Wos,
                                                     const float* __restrict__ bo2,
                                                     const float* __restrict__ x,
                                                     float* __restrict__ out) {
    __shared__ unsigned short smem[CH * KLS];   // 20736 B
    char* smc = (char*)smem;
    unsigned short* kerL = smem;

    const int tid  = threadIdx.x;
    const int wave = tid >> 6;
    const int lane = tid & 63;
    const int q    = lane >> 4;
    const int r    = lane & 15;
    const int pxh  = wave & 1;
    const int chh  = wave >> 1;
    const int p0   = blockIdx.x * 32;
    const int b    = blockIdx.y;
    const int h    = p0 >> 6;
    const int w0   = p0 & 63;
    const size_t rowbase = (size_t)b * HW + p0;

    f32x4 acc[9];
    #pragma unroll
    for (int j = 0; j < 9; ++j) acc[j] = (f32x4)0.0f;

    const int lrow = lane >> 2;
    const int lp   = lane & 3;

    for (int k0 = 0; k0 < CH; k0 += 32) {
        for (int s = wave; s < 20; s += 4) {
            const int row = s * 16 + lrow;            // 0..319
            const int sc  = lp ^ ((row >> 1) & 3);
            const unsigned short* g = (s < 18)
                ? Wos + (size_t)row * CH + k0 + sc * 8
                : xt  + (rowbase + row - 288) * CH + k0 + sc * 8;
            GLDS(g, smc + s * 1024);
        }
        __syncthreads();
        const int xr = 288 + pxh * 16 + r;
        const bf16x8 xf = *(const bf16x8*)(smc + xr * 64 + ((q ^ ((xr >> 1) & 3)) * 16));
        #pragma unroll
        for (int j = 0; j < 9; ++j) {
            const int wr = chh * 144 + j * 16 + r;
            const bf16x8 wf = *(const bf16x8*)(smc + wr * 64 + ((q ^ ((wr >> 1) & 3)) * 16));
            acc[j] = mfma16(wf, xf, acc[j]);
        }
        __syncthreads();
    }

    const int pxl = pxh * 16 + r;
    #pragma unroll
    for (int j = 0; j < 9; ++j) {
        const int cb = chh * 144 + j * 16 + q * 4;
        const float4 bz = *(const float4*)(bo2 + cb);
        kerL[(cb + 0) * KLS + pxl] = f2b(acc[j][0] + bz.x);
        kerL[(cb + 1) * KLS + pxl] = f2b(acc[j][1] + bz.y);
        kerL[(cb + 2) * KLS + pxl] = f2b(acc[j][2] + bz.z);
        kerL[(cb + 3) * KLS + pxl] = f2b(acc[j][3] + bz.w);
    }
    __syncthreads();

    const int tm = tid >> 3;
    const int tn = tid & 7;
    const int wb = w0 + tn * 4;
    #pragma unroll 1
    for (int i = 0; i < 9; ++i) {
        const int ch = tm + 32 * i;
        const int cb = (ch / CPG) * CPG;
        float xv[3][6];
        #pragma unroll
        for (int dr = 0; dr < 3; ++dr) {
            const int hh = h + dr - 1;
            const bool rv = (hh >= 0) && (hh < IMH);
            const float* xr2 = x + ((size_t)(b * CH + ch) * IMH + (rv ? hh : 0)) * IMW;
            if (rv) {
                const float4 m4 = *(const float4*)(xr2 + wb);
                xv[dr][1] = m4.x; xv[dr][2] = m4.y; xv[dr][3] = m4.z; xv[dr][4] = m4.w;
                xv[dr][0] = (wb > 0)       ? xr2[wb - 1] : 0.0f;
                xv[dr][5] = (wb + 4 < IMW) ? xr2[wb + 4] : 0.0f;
            } else {
                #pragma unroll
                for (int j = 0; j < 6; ++j) xv[dr][j] = 0.0f;
            }
        }
        float o[4] = {0.0f, 0.0f, 0.0f, 0.0f};
        #pragma unroll
        for (int k = 0; k < 9; ++k) {
            const int dr = k / 3, dc = k % 3;
            const uint2 kk = *(const uint2*)(kerL + (cb + k) * KLS + tn * 4);
            const unsigned short* ks = (const unsigned short*)&kk;
            #pragma unroll
            for (int j = 0; j < 4; ++j)
                o[j] += b2f(ks[j]) * xv[dr][j + dc];
        }
        float4 ov = {o[0], o[1], o[2], o[3]};
        *(float4*)(out + ((size_t)(b * CH + ch) * IMH + h) * IMW + wb) = ov;
    }
}

// ---------------------------------------------------------------------------
extern "C" void kernel_launch(void* const* d_in, const int* in_sizes, int n_in,
                              void* d_out, int out_size, void* d_ws, size_t ws_size,
                              hipStream_t stream) {
    const float* x     = (const float*)d_in[0];
    const float* Wi    = (const float*)d_in[1];
    const float* bi    = (const float*)d_in[2];
    const float* gamma = (const float*)d_in[3];
    const float* beta  = (const float*)d_in[4];
    const float* Wo    = (const float*)d_in[5];
    const float* bo    = (const float*)d_in[6];
    float* out = (float*)d_out;

    char* ws = (char*)d_ws;
    unsigned short* xt  = (unsigned short*)(ws + XT_OFF);
    unsigned short* Wib = (unsigned short*)(ws + WIB_OFF);
    unsigned short* Wos = (unsigned short*)(ws + WOS_OFF);
    float* s1    = (float*)(ws + S1_OFF);
    float* s2    = (float*)(ws + S2_OFF);
    float* scale = (float*)(ws + SC_OFF);
    float* shift = (float*)(ws + SH_OFF);
    float* bo2   = (float*)(ws + BO2_OFF);

    k_transpose<<<dim3(HW / 64, CH / 32, NB), 256, 0, stream>>>(x, xt);
    k_cvt_wi<<<dim3(CH * CH / 1024), 256, 0, stream>>>(Wi, Wib);
    hipMemsetAsync(ws + S1_OFF, 0, 2 * CH * sizeof(float), stream);
    k_gemm1<<<dim3(NPX / 64), 256, 0, stream>>>(Wib, bi, xt, s1);
    k_scale<<<dim3(1), 320, 0, stream>>>(s1, s2, gamma, beta, scale, shift);
    k_fold<<<dim3(CH), 64, 0, stream>>>(Wo, bo, scale, shift, Wos, bo2);
    k_gemm2_invol<<<dim3(HW / 32, NB), 256, 0, stream>>>(xt, Wos, bo2, x, out);
}

// Round 2
// 191.445 us; speedup vs baseline: 1.2024x; 1.2024x over previous
//
#include <hip/hip_runtime.h>

#define CH   288
#define GRPS 32
#define CPG  9
#define IMH  64
#define IMW  64
#define HW   4096
#define NB   8
#define NPX  (NB * HW)     // 32768 total pixel rows
#define BN_EPS 1e-5f

typedef short bf16x8 __attribute__((ext_vector_type(8)));
typedef float f32x4  __attribute__((ext_vector_type(4)));

// ws layout (bytes)
#define XT_OFF   0u            // x_t / tmp_t bf16 [b][p][c]  (18,874,368 B)
#define WIB_OFF  18874368u     // Wi bf16 [288][288]
#define WOS_OFF  19040256u     // Wo*scale bf16 [288][288]
#define S1_OFF   19206144u     // per-channel sum   f32 [288]
#define S2_OFF   19207296u     // per-channel sumsq f32 [288]  (contiguous after s1)
#define SC_OFF   19208448u     // scale f32 [288]
#define SH_OFF   19209600u     // shift f32 [288]
#define BO2_OFF  19210752u     // folded bias f32 [288]

__device__ __forceinline__ unsigned short f2b(float f) {
    unsigned int u = __float_as_uint(f);
    return (unsigned short)((u + 0x7fffu + ((u >> 16) & 1u)) >> 16);
}
__device__ __forceinline__ float b2f(unsigned short h) {
    return __uint_as_float(((unsigned int)h) << 16);
}

// async global->LDS, 16B per lane; dst = wave-uniform base + lane*16
#define GLDS(g, l) __builtin_amdgcn_global_load_lds( \
    (const __attribute__((address_space(1))) void*)(g), \
    (__attribute__((address_space(3))) void*)(l), 16, 0, 0)

__device__ __forceinline__ f32x4 mfma16(bf16x8 a, bf16x8 b, f32x4 c) {
    return __builtin_amdgcn_mfma_f32_16x16x32_bf16(a, b, c, 0, 0, 0);
}

#define SUBT 22528   // bytes per K=32 sub-tile: 352 rows x 64 B

// ---------------------------------------------------------------------------
// K0: x [b][c][p] f32 -> x_t [b][p][c] bf16 (coalesced both sides via LDS)
// ---------------------------------------------------------------------------
#define TS 40
__global__ __launch_bounds__(256) void k_transpose(const float* __restrict__ x,
                                                   unsigned short* __restrict__ xt) {
    __shared__ unsigned short T[64 * TS];
    const int tid = threadIdx.x;
    const int p0 = blockIdx.x * 64;
    const int c0 = blockIdx.y * 32;
    const int b  = blockIdx.z;
    #pragma unroll
    for (int it = 0; it < 2; ++it) {
        const int item  = it * 256 + tid;
        const int c_loc = item >> 4;
        const int p4    = item & 15;
        const float4 v = *(const float4*)(x + (size_t)(b * CH + c0 + c_loc) * HW + p0 + p4 * 4);
        const int px = p4 * 4;
        T[(px + 0) * TS + c_loc] = f2b(v.x);
        T[(px + 1) * TS + c_loc] = f2b(v.y);
        T[(px + 2) * TS + c_loc] = f2b(v.z);
        T[(px + 3) * TS + c_loc] = f2b(v.w);
    }
    __syncthreads();
    const int px_loc = tid >> 2;
    const int cq     = tid & 3;
    const uint4 o = *(const uint4*)((const char*)T + px_loc * (TS * 2) + cq * 16);
    *(uint4*)(xt + ((size_t)b * HW + p0 + px_loc) * CH + c0 + cq * 8) = o;
}

// ---------------------------------------------------------------------------
// K0b: Wi f32 -> bf16
// ---------------------------------------------------------------------------
__global__ __launch_bounds__(256) void k_cvt_wi(const float* __restrict__ Wi,
                                                unsigned short* __restrict__ Wib) {
    const int idx = blockIdx.x * 256 + threadIdx.x;
    const float4 v = ((const float4*)Wi)[idx];
    unsigned short h[4] = {f2b(v.x), f2b(v.y), f2b(v.z), f2b(v.w)};
    *(uint2*)(Wib + (size_t)idx * 4) = *(const uint2*)h;
}

// ---------------------------------------------------------------------------
// K1: LDS-staged MFMA GEMM1 + fused BN stats.  BK=96 (3 K-iterations).
//   tmp_t[px][c] = relu(dot(x_t[px][:], Wi[c][:]) + bi[c])  (bf16, in-place)
// Block: 64 px x 288 c, 4 waves; wave = 32 px x 144 c (2x9 MFMA tiles x 3 kk).
// LDS: 3 sub-tiles of 352 rows x 64 B (rows 0..63 = x, 64..351 = Wi),
// XOR chunk swizzle per 64-B row slice. 3 drains/block instead of 9.
// ---------------------------------------------------------------------------
__global__ __launch_bounds__(256) void k_gemm1(const unsigned short* __restrict__ Wib,
                                               const float* __restrict__ bi,
                                               unsigned short* __restrict__ xt,
                                               float* __restrict__ s1g) {
    __shared__ unsigned short smem[3 * 11264];   // 67584 B
    char* smc = (char*)smem;

    const int tid  = threadIdx.x;
    const int wave = tid >> 6;
    const int lane = tid & 63;
    const int q    = lane >> 4;
    const int r    = lane & 15;
    const int pxh  = wave & 1;      // 32-px half
    const int chh  = wave >> 1;     // 144-c half
    const int p0   = blockIdx.x * 64;

    f32x4 acc[2][9];
    #pragma unroll
    for (int t = 0; t < 2; ++t)
        #pragma unroll
        for (int j = 0; j < 9; ++j) acc[t][j] = (f32x4)0.0f;

    const int lrow = lane >> 2;          // staging: row within segment
    const int lp   = lane & 3;           // staging: chunk position

    for (int k0 = 0; k0 < CH; k0 += 96) {
        // ---- stage 3 x 22 segments of 1KB (4 x-tile + 18 Wi-tile each) ----
        #pragma unroll
        for (int kk = 0; kk < 3; ++kk) {
            for (int s = wave; s < 22; s += 4) {
                const int row = s * 16 + lrow;           // LDS row 0..351
                const int sc  = lp ^ ((row >> 1) & 3);   // swizzled source chunk
                const unsigned short* g = (s < 4)
                    ? xt  + (size_t)(p0 + row) * CH + k0 + kk * 32 + sc * 8
                    : Wib + (size_t)(row - 64) * CH + k0 + kk * 32 + sc * 8;
                GLDS(g, smc + kk * SUBT + s * 1024);
            }
        }
        __syncthreads();
        // ---- compute: 54 MFMA per wave per drain ----
        bf16x8 xf[3][2];
        #pragma unroll
        for (int kk = 0; kk < 3; ++kk)
            #pragma unroll
            for (int t = 0; t < 2; ++t) {
                const int row = pxh * 32 + t * 16 + r;
                xf[kk][t] = *(const bf16x8*)(smc + kk * SUBT + row * 64 + ((q ^ ((row >> 1) & 3)) * 16));
            }
        #pragma unroll
        for (int j = 0; j < 9; ++j) {
            const int ro = 64 + chh * 144 + j * 16 + r;
            #pragma unroll
            for (int kk = 0; kk < 3; ++kk) {
                const bf16x8 wf = *(const bf16x8*)(smc + kk * SUBT + ro * 64 + ((q ^ ((ro >> 1) & 3)) * 16));
                acc[0][j] = mfma16(wf, xf[kk][0], acc[0][j]);
                acc[1][j] = mfma16(wf, xf[kk][1], acc[1][j]);
            }
        }
        __syncthreads();
    }

    // ================= epilogue =================
    // LDS reuse: bytes [0, 18432) = 32-row x 576 B output staging (per phase),
    //            bytes [18432, 20736) = 576-float stats accumulator.
    float* sstat = (float*)(smc + 18432);
    for (int c2 = tid; c2 < 576; c2 += 256) sstat[c2] = 0.0f;
    __syncthreads();

    // ---- BN stats: per-wave shfl reduce over r, LDS atomic accumulate ----
    #pragma unroll 1
    for (int j = 0; j < 9; ++j) {
        const int cb = chh * 144 + j * 16 + q * 4;
        const float4 b4 = *(const float4*)(bi + cb);
        float a1[4] = {0.f, 0.f, 0.f, 0.f}, a2[4] = {0.f, 0.f, 0.f, 0.f};
        #pragma unroll
        for (int t = 0; t < 2; ++t) {
            float v0 = fmaxf(acc[t][j][0] + b4.x, 0.0f);
            float v1 = fmaxf(acc[t][j][1] + b4.y, 0.0f);
            float v2 = fmaxf(acc[t][j][2] + b4.z, 0.0f);
            float v3 = fmaxf(acc[t][j][3] + b4.w, 0.0f);
            a1[0] += v0; a1[1] += v1; a1[2] += v2; a1[3] += v3;
            a2[0] += v0 * v0; a2[1] += v1 * v1; a2[2] += v2 * v2; a2[3] += v3 * v3;
        }
        #pragma unroll
        for (int m = 1; m < 16; m <<= 1) {
            #pragma unroll
            for (int i = 0; i < 4; ++i) {
                a1[i] += __shfl_xor(a1[i], m, 64);
                a2[i] += __shfl_xor(a2[i], m, 64);
            }
        }
        if (r == 0) {
            #pragma unroll
            for (int i = 0; i < 4; ++i) {
                atomicAdd(&sstat[cb + i], a1[i]);
                atomicAdd(&sstat[288 + cb + i], a2[i]);
            }
        }
    }

    // ---- two-phase coalesced store of the 64x288 bf16 tile ----
    #pragma unroll
    for (int ph = 0; ph < 2; ++ph) {
        // stage: this wave's 16-px x 144-c piece for phase ph
        const int lr = pxh * 16 + r;     // local row 0..31
        #pragma unroll
        for (int j = 0; j < 9; ++j) {
            const int cb = chh * 144 + j * 16 + q * 4;
            const float4 b4 = *(const float4*)(bi + cb);
            unsigned short h[4];
            h[0] = f2b(fmaxf(acc[ph][j][0] + b4.x, 0.0f));
            h[1] = f2b(fmaxf(acc[ph][j][1] + b4.y, 0.0f));
            h[2] = f2b(fmaxf(acc[ph][j][2] + b4.z, 0.0f));
            h[3] = f2b(fmaxf(acc[ph][j][3] + b4.w, 0.0f));
            *(uint2*)(smc + lr * 576 + cb * 2) = *(const uint2*)h;
        }
        __syncthreads();
        // cooperative contiguous store: 32 rows x 36 chunks of 16 B
        for (int idx = tid; idx < 1152; idx += 256) {
            const int row = idx / 36;
            const int off = idx - row * 36;
            const int gpx = p0 + ph * 16 + row + (row & 16);
            *(uint4*)(xt + (size_t)gpx * CH + off * 8) =
                *(const uint4*)(smc + row * 576 + off * 16);
        }
        if (ph == 0) {
            // flush stats (s2g is contiguous after s1g in ws)
            for (int c2 = tid; c2 < 576; c2 += 256)
                atomicAdd(&s1g[c2], sstat[c2]);
        }
        __syncthreads();
    }
}

// ---------------------------------------------------------------------------
// K2a: BN scale/shift
// ---------------------------------------------------------------------------
__global__ __launch_bounds__(320) void k_scale(const float* __restrict__ s1,
                                               const float* __restrict__ s2,
                                               const float* __restrict__ gamma,
                                               const float* __restrict__ beta,
                                               float* __restrict__ scale,
                                               float* __restrict__ shift) {
    const int c = threadIdx.x;
    if (c < CH) {
        const float inv = 1.0f / (float)(NB * HW);
        const float mean = s1[c] * inv;
        const float var  = s2[c] * inv - mean * mean;
        const float rs   = rsqrtf(var + BN_EPS);
        const float sc   = gamma[c] * rs;
        scale[c] = sc;
        shift[c] = beta[c] - mean * sc;
    }
}

// ---------------------------------------------------------------------------
// K2b: Wo_s[m][k] = bf16(Wo[m][k]*scale[k]); bo2[m] = bo[m] + Wo[m][:]@shift
// ---------------------------------------------------------------------------
__global__ __launch_bounds__(64) void k_fold(const float* __restrict__ Wo,
                                             const float* __restrict__ bo,
                                             const float* __restrict__ scale,
                                             const float* __restrict__ shift,
                                             unsigned short* __restrict__ Wos,
                                             float* __restrict__ bo2) {
    const int m = blockIdx.x;
    const int t = threadIdx.x;
    float s = 0.0f;
    for (int k = t; k < CH; k += 64) {
        const float wv = Wo[(size_t)m * CH + k];
        s += wv * shift[k];
        Wos[(size_t)m * CH + k] = f2b(wv * scale[k]);
    }
    #pragma unroll
    for (int off = 32; off > 0; off >>= 1) s += __shfl_down(s, off, 64);
    if (t == 0) bo2[m] = bo[m] + s;
}

// ---------------------------------------------------------------------------
// K3: LDS-staged MFMA GEMM2 (ker = Wo_s @ tmp + bo2) -> kerL -> involution.
// BK=96 (3 K-iterations), 64-px blocks (halves Wos staging volume vs 32-px).
// Block: 64 px x 288 ker-ch, 4 waves; wave = 32 px x 144 c (2x9 tiles x 3 kk).
// LDS: 3 sub-tiles of 352 rows x 64 B (rows 0..287 = Wos, 288..351 = x rows).
// ---------------------------------------------------------------------------
#define KLS2 68
__global__ __launch_bounds__(256) void k_gemm2_invol(const unsigned short* __restrict__ xt,
                                                     const unsigned short* __restrict__ Wos,
                                                     const float* __restrict__ bo2,
                                                     const float* __restrict__ x,
                                                     float* __restrict__ out) {
    __shared__ unsigned short smem[3 * 11264];   // 67584 B; kerL reuses [0, 39168)
    char* smc = (char*)smem;
    unsigned short* kerL = smem;

    const int tid  = threadIdx.x;
    const int wave = tid >> 6;
    const int lane = tid & 63;
    const int q    = lane >> 4;
    const int r    = lane & 15;
    const int pxh  = wave & 1;
    const int chh  = wave >> 1;
    const int p0   = blockIdx.x * 64;    // 64 px = one full image row
    const int b    = blockIdx.y;
    const int h    = blockIdx.x;
    const size_t rowbase = (size_t)b * HW + p0;

    f32x4 acc[2][9];
    #pragma unroll
    for (int t = 0; t < 2; ++t)
        #pragma unroll
        for (int j = 0; j < 9; ++j) acc[t][j] = (f32x4)0.0f;

    const int lrow = lane >> 2;
    const int lp   = lane & 3;

    for (int k0 = 0; k0 < CH; k0 += 96) {
        #pragma unroll
        for (int kk = 0; kk < 3; ++kk) {
            for (int s = wave; s < 22; s += 4) {
                const int row = s * 16 + lrow;            // 0..351
                const int sc  = lp ^ ((row >> 1) & 3);
                const unsigned short* g = (s < 18)
                    ? Wos + (size_t)row * CH + k0 + kk * 32 + sc * 8
                    : xt  + (rowbase + row - 288) * CH + k0 + kk * 32 + sc * 8;
                GLDS(g, smc + kk * SUBT + s * 1024);
            }
        }
        __syncthreads();
        bf16x8 xf[3][2];
        #pragma unroll
        for (int kk = 0; kk < 3; ++kk)
            #pragma unroll
            for (int t = 0; t < 2; ++t) {
                const int xr = 288 + pxh * 32 + t * 16 + r;
                xf[kk][t] = *(const bf16x8*)(smc + kk * SUBT + xr * 64 + ((q ^ ((xr >> 1) & 3)) * 16));
            }
        #pragma unroll
        for (int j = 0; j < 9; ++j) {
            const int wr = chh * 144 + j * 16 + r;
            #pragma unroll
            for (int kk = 0; kk < 3; ++kk) {
                const bf16x8 wf = *(const bf16x8*)(smc + kk * SUBT + wr * 64 + ((q ^ ((wr >> 1) & 3)) * 16));
                acc[0][j] = mfma16(wf, xf[kk][0], acc[0][j]);
                acc[1][j] = mfma16(wf, xf[kk][1], acc[1][j]);
            }
        }
        __syncthreads();
    }

    // ---- stage ker tile to LDS: kerL[ch][px], 288 x 64 (stride 68) ----
    #pragma unroll
    for (int j = 0; j < 9; ++j) {
        const int cb = chh * 144 + j * 16 + q * 4;
        const float4 bz = *(const float4*)(bo2 + cb);
        #pragma unroll
        for (int t = 0; t < 2; ++t) {
            const int pxl = pxh * 32 + t * 16 + r;
            kerL[(cb + 0) * KLS2 + pxl] = f2b(acc[t][j][0] + bz.x);
            kerL[(cb + 1) * KLS2 + pxl] = f2b(acc[t][j][1] + bz.y);
            kerL[(cb + 2) * KLS2 + pxl] = f2b(acc[t][j][2] + bz.z);
            kerL[(cb + 3) * KLS2 + pxl] = f2b(acc[t][j][3] + bz.w);
        }
    }
    __syncthreads();

    // ---- involution: 256 threads, 16 ch x 64 w per iteration, 18 iters ----
    const int tm = tid >> 4;         // 0..15  (channel)
    const int tn = tid & 15;         // 0..15  (w quad)
    const int wb = tn * 4;
    #pragma unroll 1
    for (int i = 0; i < 18; ++i) {
        const int ch = tm + 16 * i;
        const int cb = (ch / CPG) * CPG;
        float xv[3][6];
        #pragma unroll
        for (int dr = 0; dr < 3; ++dr) {
            const int hh = h + dr - 1;
            const bool rv = (hh >= 0) && (hh < IMH);
            const float* xr2 = x + ((size_t)(b * CH + ch) * IMH + (rv ? hh : 0)) * IMW;
            if (rv) {
                const float4 m4 = *(const float4*)(xr2 + wb);
                xv[dr][1] = m4.x; xv[dr][2] = m4.y; xv[dr][3] = m4.z; xv[dr][4] = m4.w;
                xv[dr][0] = (wb > 0)       ? xr2[wb - 1] : 0.0f;
                xv[dr][5] = (wb + 4 < IMW) ? xr2[wb + 4] : 0.0f;
            } else {
                #pragma unroll
                for (int j = 0; j < 6; ++j) xv[dr][j] = 0.0f;
            }
        }
        float o[4] = {0.0f, 0.0f, 0.0f, 0.0f};
        #pragma unroll
        for (int k = 0; k < 9; ++k) {
            const int dr = k / 3, dc = k % 3;
            const uint2 kk = *(const uint2*)(kerL + (cb + k) * KLS2 + tn * 4);
            const unsigned short* ks = (const unsigned short*)&kk;
            #pragma unroll
            for (int j = 0; j < 4; ++j)
                o[j] += b2f(ks[j]) * xv[dr][j + dc];
        }
        float4 ov = {o[0], o[1], o[2], o[3]};
        *(float4*)(out + ((size_t)(b * CH + ch) * IMH + h) * IMW + wb) = ov;
    }
}

// ---------------------------------------------------------------------------
extern "C" void kernel_launch(void* const* d_in, const int* in_sizes, int n_in,
                              void* d_out, int out_size, void* d_ws, size_t ws_size,
                              hipStream_t stream) {
    const float* x     = (const float*)d_in[0];
    const float* Wi    = (const float*)d_in[1];
    const float* bi    = (const float*)d_in[2];
    const float* gamma = (const float*)d_in[3];
    const float* beta  = (const float*)d_in[4];
    const float* Wo    = (const float*)d_in[5];
    const float* bo    = (const float*)d_in[6];
    float* out = (float*)d_out;

    char* ws = (char*)d_ws;
    unsigned short* xt  = (unsigned short*)(ws + XT_OFF);
    unsigned short* Wib = (unsigned short*)(ws + WIB_OFF);
    unsigned short* Wos = (unsigned short*)(ws + WOS_OFF);
    float* s1    = (float*)(ws + S1_OFF);
    float* s2    = (float*)(ws + S2_OFF);
    float* scale = (float*)(ws + SC_OFF);
    float* shift = (float*)(ws + SH_OFF);
    float* bo2   = (float*)(ws + BO2_OFF);

    k_transpose<<<dim3(HW / 64, CH / 32, NB), 256, 0, stream>>>(x, xt);
    k_cvt_wi<<<dim3(CH * CH / 1024), 256, 0, stream>>>(Wi, Wib);
    hipMemsetAsync(ws + S1_OFF, 0, 2 * CH * sizeof(float), stream);
    k_gemm1<<<dim3(NPX / 64), 256, 0, stream>>>(Wib, bi, xt, s1);
    k_scale<<<dim3(1), 320, 0, stream>>>(s1, s2, gamma, beta, scale, shift);
    k_fold<<<dim3(CH), 64, 0, stream>>>(Wo, bo, scale, shift, Wos, bo2);
    k_gemm2_invol<<<dim3(HW / 64, NB), 256, 0, stream>>>(xt, Wos, bo2, x, out);
}

// Round 3
// 186.547 us; speedup vs baseline: 1.2340x; 1.0263x over previous
//
#include <hip/hip_runtime.h>

#define CH   288
#define GRPS 32
#define CPG  9
#define IMH  64
#define IMW  64
#define HW   4096
#define NB   8
#define NPX  (NB * HW)     // 32768 total pixel rows
#define BN_EPS 1e-5f

typedef short bf16x8 __attribute__((ext_vector_type(8)));
typedef float f32x4  __attribute__((ext_vector_type(4)));

// ws layout (bytes)
#define XT_OFF   0u            // x_t / tmp_t bf16 [b][p][c]  (18,874,368 B)
#define WIB_OFF  18874368u     // Wi bf16 [288][288]
#define WOS_OFF  19040256u     // Wo*scale bf16 [288][288]
#define S1_OFF   19206144u     // per-channel sum   f32 [288]
#define S2_OFF   19207296u     // per-channel sumsq f32 [288]  (contiguous after s1)
#define SC_OFF   19208448u     // scale f32 [288]
#define SH_OFF   19209600u     // shift f32 [288]
#define BO2_OFF  19210752u     // folded bias f32 [288]

// LDS region layout for the GEMM kernels (73728 B total, 2 blocks/CU):
//   X region  [0, 36864):      64 px rows x 576 B (full K=288), XOR-swizzled
//   W buf0    [36864, 55296):  288 rows x 64 B (one BK=32 K-slice)
//   W buf1    [55296, 73728)
#define XB 36864
#define WB 18432

__device__ __forceinline__ unsigned short f2b(float f) {
    unsigned int u = __float_as_uint(f);
    return (unsigned short)((u + 0x7fffu + ((u >> 16) & 1u)) >> 16);
}
__device__ __forceinline__ float b2f(unsigned short h) {
    return __uint_as_float(((unsigned int)h) << 16);
}

// async global->LDS, 16B per lane; dst = wave-uniform base + lane*16
#define GLDS(g, l) __builtin_amdgcn_global_load_lds( \
    (const __attribute__((address_space(1))) void*)(g), \
    (__attribute__((address_space(3))) void*)(l), 16, 0, 0)

__device__ __forceinline__ f32x4 mfma16(bf16x8 a, bf16x8 b, f32x4 c) {
    return __builtin_amdgcn_mfma_f32_16x16x32_bf16(a, b, c, 0, 0, 0);
}

// ---------------------------------------------------------------------------
// K0: x [b][c][p] f32 -> x_t [b][p][c] bf16 (coalesced both sides via LDS)
// ---------------------------------------------------------------------------
#define TS 40
__global__ __launch_bounds__(256) void k_transpose(const float* __restrict__ x,
                                                   unsigned short* __restrict__ xt) {
    __shared__ unsigned short T[64 * TS];
    const int tid = threadIdx.x;
    const int p0 = blockIdx.x * 64;
    const int c0 = blockIdx.y * 32;
    const int b  = blockIdx.z;
    #pragma unroll
    for (int it = 0; it < 2; ++it) {
        const int item  = it * 256 + tid;
        const int c_loc = item >> 4;
        const int p4    = item & 15;
        const float4 v = *(const float4*)(x + (size_t)(b * CH + c0 + c_loc) * HW + p0 + p4 * 4);
        const int px = p4 * 4;
        T[(px + 0) * TS + c_loc] = f2b(v.x);
        T[(px + 1) * TS + c_loc] = f2b(v.y);
        T[(px + 2) * TS + c_loc] = f2b(v.z);
        T[(px + 3) * TS + c_loc] = f2b(v.w);
    }
    __syncthreads();
    const int px_loc = tid >> 2;
    const int cq     = tid & 3;
    const uint4 o = *(const uint4*)((const char*)T + px_loc * (TS * 2) + cq * 16);
    *(uint4*)(xt + ((size_t)b * HW + p0 + px_loc) * CH + c0 + cq * 8) = o;
}

// ---------------------------------------------------------------------------
// K0b: Wi f32 -> bf16
// ---------------------------------------------------------------------------
__global__ __launch_bounds__(256) void k_cvt_wi(const float* __restrict__ Wi,
                                                unsigned short* __restrict__ Wib) {
    const int idx = blockIdx.x * 256 + threadIdx.x;
    const float4 v = ((const float4*)Wi)[idx];
    unsigned short h[4] = {f2b(v.x), f2b(v.y), f2b(v.z), f2b(v.w)};
    *(uint2*)(Wib + (size_t)idx * 4) = *(const uint2*)h;
}

// Shared compute macro: one BK=32 K-step, 18 MFMA per wave.
// X fragment from X region at k-chunk KK; W fragments from WBASE buffer.
#define GEMM_STEP(KK, WBASE) do {                                              \
    bf16x8 xf0, xf1;                                                           \
    { const int row0 = pxh * 32 + r;                                           \
      xf0 = *(const bf16x8*)(smc + row0 * 576 + (KK) * 64 +                    \
                             ((q ^ ((row0 >> 1) & 3)) * 16)); }                \
    { const int row1 = pxh * 32 + 16 + r;                                      \
      xf1 = *(const bf16x8*)(smc + row1 * 576 + (KK) * 64 +                    \
                             ((q ^ ((row1 >> 1) & 3)) * 16)); }                \
    _Pragma("unroll")                                                          \
    for (int j = 0; j < 9; ++j) {                                              \
        const int ro = chh * 144 + j * 16 + r;                                 \
        const bf16x8 wf = *(const bf16x8*)((WBASE) + ro * 64 +                 \
                             ((q ^ ((ro >> 1) & 3)) * 16));                    \
        acc[0][j] = mfma16(wf, xf0, acc[0][j]);                                \
        acc[1][j] = mfma16(wf, xf1, acc[1][j]);                                \
    }                                                                          \
} while (0)

// Stage one BK=32 W slice (288 rows x 64 B) into WDST; 18 x 1KB segments,
// waves 0,1 issue 5 GLDS, waves 2,3 issue 4.
#define STAGE_W(WSRC, K0v, WDST) do {                                          \
    for (int s = wave; s < 18; s += 4) {                                       \
        const int row = s * 16 + lrow;                                         \
        const int sc  = lp ^ ((row >> 1) & 3);                                 \
        GLDS((WSRC) + (size_t)row * CH + (K0v) + sc * 8, (WDST) + s * 1024);   \
    }                                                                          \
} while (0)

// Stage the 64-row x full-K X tile (36 KB contiguous in global) into the X
// region with XOR swizzle applied via per-lane source addressing (m173).
#define STAGE_X(XSRC) do {                                                     \
    for (int s = wave; s < 36; s += 4) {                                       \
        const int d   = s * 1024 + lane * 16;                                  \
        const int px  = d / 576;                                               \
        const int rem = d - px * 576;                                          \
        const int kc  = rem >> 6;                                              \
        const int ch  = (rem >> 4) & 3;                                        \
        const int sc  = ch ^ ((px >> 1) & 3);                                  \
        GLDS((XSRC) + (size_t)px * CH + kc * 32 + sc * 8, smc + s * 1024);     \
    }                                                                          \
} while (0)

// ---------------------------------------------------------------------------
// K1: pipelined MFMA GEMM1 + fused BN stats.
//   tmp_t[px][c] = relu(dot(x_t[px][:], Wi[c][:]) + bi[c])  (bf16, in-place)
// Block: 64 px x 288 c, 4 waves; wave = 32 px x 144 c.
// X tile (full K) staged once; Wi double-buffered BK=32 with counted vmcnt(4)
// — one vmcnt(0) drain total (prologue), never in the main loop.
// ---------------------------------------------------------------------------
__global__ __launch_bounds__(256) void k_gemm1(const unsigned short* __restrict__ Wib,
                                               const float* __restrict__ bi,
                                               unsigned short* __restrict__ xt,
                                               float* __restrict__ s1g) {
    __shared__ char smc[XB + 2 * WB];   // 73728 B

    const int tid  = threadIdx.x;
    const int wave = tid >> 6;
    const int lane = tid & 63;
    const int q    = lane >> 4;
    const int r    = lane & 15;
    const int pxh  = wave & 1;      // 32-px half
    const int chh  = wave >> 1;     // 144-c half
    const int p0   = blockIdx.x * 64;
    const int lrow = lane >> 2;
    const int lp   = lane & 3;

    f32x4 acc[2][9];
    #pragma unroll
    for (int t = 0; t < 2; ++t)
        #pragma unroll
        for (int j = 0; j < 9; ++j) acc[t][j] = (f32x4)0.0f;

    // ---- prologue: X tile (once) + Wi slice 0; single full drain ----
    STAGE_X(xt + (size_t)p0 * CH);
    STAGE_W(Wib, 0, smc + XB);
    asm volatile("s_waitcnt vmcnt(0)" ::: "memory");
    __builtin_amdgcn_s_barrier();

    // ---- pipelined K-loop: stage kk+1, counted wait, compute kk ----
    #pragma unroll 1
    for (int kk = 0; kk < 8; ++kk) {
        char* wnext = smc + XB + ((kk + 1) & 1) * WB;
        STAGE_W(Wib, (kk + 1) * 32, wnext);
        asm volatile("s_waitcnt vmcnt(4)" ::: "memory");
        __builtin_amdgcn_s_barrier();
        char* wcur = smc + XB + (kk & 1) * WB;
        GEMM_STEP(kk, wcur);
        __builtin_amdgcn_s_barrier();
    }
    asm volatile("s_waitcnt vmcnt(0)" ::: "memory");
    __builtin_amdgcn_s_barrier();
    GEMM_STEP(8, smc + XB);
    __syncthreads();

    // ================= epilogue =================
    // LDS reuse: bytes [0, 18432) = 32-row x 576 B output staging (per phase),
    //            bytes [18432, 20736) = 576-float stats accumulator.
    float* sstat = (float*)(smc + 18432);
    for (int c2 = tid; c2 < 576; c2 += 256) sstat[c2] = 0.0f;
    __syncthreads();

    // ---- BN stats: per-wave shfl reduce over r, LDS atomic accumulate ----
    #pragma unroll 1
    for (int j = 0; j < 9; ++j) {
        const int cb = chh * 144 + j * 16 + q * 4;
        const float4 b4 = *(const float4*)(bi + cb);
        float a1[4] = {0.f, 0.f, 0.f, 0.f}, a2[4] = {0.f, 0.f, 0.f, 0.f};
        #pragma unroll
        for (int t = 0; t < 2; ++t) {
            float v0 = fmaxf(acc[t][j][0] + b4.x, 0.0f);
            float v1 = fmaxf(acc[t][j][1] + b4.y, 0.0f);
            float v2 = fmaxf(acc[t][j][2] + b4.z, 0.0f);
            float v3 = fmaxf(acc[t][j][3] + b4.w, 0.0f);
            a1[0] += v0; a1[1] += v1; a1[2] += v2; a1[3] += v3;
            a2[0] += v0 * v0; a2[1] += v1 * v1; a2[2] += v2 * v2; a2[3] += v3 * v3;
        }
        #pragma unroll
        for (int m = 1; m < 16; m <<= 1) {
            #pragma unroll
            for (int i = 0; i < 4; ++i) {
                a1[i] += __shfl_xor(a1[i], m, 64);
                a2[i] += __shfl_xor(a2[i], m, 64);
            }
        }
        if (r == 0) {
            #pragma unroll
            for (int i = 0; i < 4; ++i) {
                atomicAdd(&sstat[cb + i], a1[i]);
                atomicAdd(&sstat[288 + cb + i], a2[i]);
            }
        }
    }

    // ---- two-phase coalesced store of the 64x288 bf16 tile ----
    #pragma unroll
    for (int ph = 0; ph < 2; ++ph) {
        const int lr = pxh * 16 + r;     // local row 0..31
        #pragma unroll
        for (int j = 0; j < 9; ++j) {
            const int cb = chh * 144 + j * 16 + q * 4;
            const float4 b4 = *(const float4*)(bi + cb);
            unsigned short h[4];
            h[0] = f2b(fmaxf(acc[ph][j][0] + b4.x, 0.0f));
            h[1] = f2b(fmaxf(acc[ph][j][1] + b4.y, 0.0f));
            h[2] = f2b(fmaxf(acc[ph][j][2] + b4.z, 0.0f));
            h[3] = f2b(fmaxf(acc[ph][j][3] + b4.w, 0.0f));
            *(uint2*)(smc + lr * 576 + cb * 2) = *(const uint2*)h;
        }
        __syncthreads();
        for (int idx = tid; idx < 1152; idx += 256) {
            const int row = idx / 36;
            const int off = idx - row * 36;
            const int gpx = p0 + ph * 16 + row + (row & 16);
            *(uint4*)(xt + (size_t)gpx * CH + off * 8) =
                *(const uint4*)(smc + row * 576 + off * 16);
        }
        if (ph == 0) {
            for (int c2 = tid; c2 < 576; c2 += 256)
                atomicAdd(&s1g[c2], sstat[c2]);
        }
        __syncthreads();
    }
}

// ---------------------------------------------------------------------------
// K2a: BN scale/shift
// ---------------------------------------------------------------------------
__global__ __launch_bounds__(320) void k_scale(const float* __restrict__ s1,
                                               const float* __restrict__ s2,
                                               const float* __restrict__ gamma,
                                               const float* __restrict__ beta,
                                               float* __restrict__ scale,
                                               float* __restrict__ shift) {
    const int c = threadIdx.x;
    if (c < CH) {
        const float inv = 1.0f / (float)(NB * HW);
        const float mean = s1[c] * inv;
        const float var  = s2[c] * inv - mean * mean;
        const float rs   = rsqrtf(var + BN_EPS);
        const float sc   = gamma[c] * rs;
        scale[c] = sc;
        shift[c] = beta[c] - mean * sc;
    }
}

// ---------------------------------------------------------------------------
// K2b: Wo_s[m][k] = bf16(Wo[m][k]*scale[k]); bo2[m] = bo[m] + Wo[m][:]@shift
// ---------------------------------------------------------------------------
__global__ __launch_bounds__(64) void k_fold(const float* __restrict__ Wo,
                                             const float* __restrict__ bo,
                                             const float* __restrict__ scale,
                                             const float* __restrict__ shift,
                                             unsigned short* __restrict__ Wos,
                                             float* __restrict__ bo2) {
    const int m = blockIdx.x;
    const int t = threadIdx.x;
    float s = 0.0f;
    for (int k = t; k < CH; k += 64) {
        const float wv = Wo[(size_t)m * CH + k];
        s += wv * shift[k];
        Wos[(size_t)m * CH + k] = f2b(wv * scale[k]);
    }
    #pragma unroll
    for (int off = 32; off > 0; off >>= 1) s += __shfl_down(s, off, 64);
    if (t == 0) bo2[m] = bo[m] + s;
}

// ---------------------------------------------------------------------------
// K3: pipelined MFMA GEMM2 (ker = Wo_s @ tmp + bo2) -> kerL -> involution.
// Same pipeline structure as K1: tmp tile staged once, Wos double-buffered.
// Block: 64 px (one image row) x 288 ker-ch, 4 waves.
// ---------------------------------------------------------------------------
#define KLS2 68
__global__ __launch_bounds__(256) void k_gemm2_invol(const unsigned short* __restrict__ xt,
                                                     const unsigned short* __restrict__ Wos,
                                                     const float* __restrict__ bo2,
                                                     const float* __restrict__ x,
                                                     float* __restrict__ out) {
    __shared__ char smc[XB + 2 * WB];   // 73728 B; kerL reuses [0, 39168)
    unsigned short* kerL = (unsigned short*)smc;

    const int tid  = threadIdx.x;
    const int wave = tid >> 6;
    const int lane = tid & 63;
    const int q    = lane >> 4;
    const int r    = lane & 15;
    const int pxh  = wave & 1;
    const int chh  = wave >> 1;
    const int p0   = blockIdx.x * 64;    // 64 px = one full image row
    const int b    = blockIdx.y;
    const int h    = blockIdx.x;
    const size_t rowbase = (size_t)b * HW + p0;
    const int lrow = lane >> 2;
    const int lp   = lane & 3;

    f32x4 acc[2][9];
    #pragma unroll
    for (int t = 0; t < 2; ++t)
        #pragma unroll
        for (int j = 0; j < 9; ++j) acc[t][j] = (f32x4)0.0f;

    // ---- prologue ----
    STAGE_X(xt + rowbase * CH);
    STAGE_W(Wos, 0, smc + XB);
    asm volatile("s_waitcnt vmcnt(0)" ::: "memory");
    __builtin_amdgcn_s_barrier();

    #pragma unroll 1
    for (int kk = 0; kk < 8; ++kk) {
        char* wnext = smc + XB + ((kk + 1) & 1) * WB;
        STAGE_W(Wos, (kk + 1) * 32, wnext);
        asm volatile("s_waitcnt vmcnt(4)" ::: "memory");
        __builtin_amdgcn_s_barrier();
        char* wcur = smc + XB + (kk & 1) * WB;
        GEMM_STEP(kk, wcur);
        __builtin_amdgcn_s_barrier();
    }
    asm volatile("s_waitcnt vmcnt(0)" ::: "memory");
    __builtin_amdgcn_s_barrier();
    GEMM_STEP(8, smc + XB);
    __syncthreads();

    // ---- stage ker tile to LDS: kerL[ch][px], 288 x 64 (stride 68) ----
    #pragma unroll
    for (int j = 0; j < 9; ++j) {
        const int cb = chh * 144 + j * 16 + q * 4;
        const float4 bz = *(const float4*)(bo2 + cb);
        #pragma unroll
        for (int t = 0; t < 2; ++t) {
            const int pxl = pxh * 32 + t * 16 + r;
            kerL[(cb + 0) * KLS2 + pxl] = f2b(acc[t][j][0] + bz.x);
            kerL[(cb + 1) * KLS2 + pxl] = f2b(acc[t][j][1] + bz.y);
            kerL[(cb + 2) * KLS2 + pxl] = f2b(acc[t][j][2] + bz.z);
            kerL[(cb + 3) * KLS2 + pxl] = f2b(acc[t][j][3] + bz.w);
        }
    }
    __syncthreads();

    // ---- involution: 256 threads, 16 ch x 64 w per iteration, 18 iters ----
    const int tm = tid >> 4;         // 0..15  (channel)
    const int tn = tid & 15;         // 0..15  (w quad)
    const int wb = tn * 4;
    #pragma unroll 1
    for (int i = 0; i < 18; ++i) {
        const int ch = tm + 16 * i;
        const int cb = (ch / CPG) * CPG;
        float xv[3][6];
        #pragma unroll
        for (int dr = 0; dr < 3; ++dr) {
            const int hh = h + dr - 1;
            const bool rv = (hh >= 0) && (hh < IMH);
            const float* xr2 = x + ((size_t)(b * CH + ch) * IMH + (rv ? hh : 0)) * IMW;
            if (rv) {
                const float4 m4 = *(const float4*)(xr2 + wb);
                xv[dr][1] = m4.x; xv[dr][2] = m4.y; xv[dr][3] = m4.z; xv[dr][4] = m4.w;
                xv[dr][0] = (wb > 0)       ? xr2[wb - 1] : 0.0f;
                xv[dr][5] = (wb + 4 < IMW) ? xr2[wb + 4] : 0.0f;
            } else {
                #pragma unroll
                for (int j = 0; j < 6; ++j) xv[dr][j] = 0.0f;
            }
        }
        float o[4] = {0.0f, 0.0f, 0.0f, 0.0f};
        #pragma unroll
        for (int k = 0; k < 9; ++k) {
            const int dr = k / 3, dc = k % 3;
            const uint2 kk = *(const uint2*)(kerL + (cb + k) * KLS2 + tn * 4);
            const unsigned short* ks = (const unsigned short*)&kk;
            #pragma unroll
            for (int j = 0; j < 4; ++j)
                o[j] += b2f(ks[j]) * xv[dr][j + dc];
        }
        float4 ov = {o[0], o[1], o[2], o[3]};
        *(float4*)(out + ((size_t)(b * CH + ch) * IMH + h) * IMW + wb) = ov;
    }
}

// ---------------------------------------------------------------------------
extern "C" void kernel_launch(void* const* d_in, const int* in_sizes, int n_in,
                              void* d_out, int out_size, void* d_ws, size_t ws_size,
                              hipStream_t stream) {
    const float* x     = (const float*)d_in[0];
    const float* Wi    = (const float*)d_in[1];
    const float* bi    = (const float*)d_in[2];
    const float* gamma = (const float*)d_in[3];
    const float* beta  = (const float*)d_in[4];
    const float* Wo    = (const float*)d_in[5];
    const float* bo    = (const float*)d_in[6];
    float* out = (float*)d_out;

    char* ws = (char*)d_ws;
    unsigned short* xt  = (unsigned short*)(ws + XT_OFF);
    unsigned short* Wib = (unsigned short*)(ws + WIB_OFF);
    unsigned short* Wos = (unsigned short*)(ws + WOS_OFF);
    float* s1    = (float*)(ws + S1_OFF);
    float* s2    = (float*)(ws + S2_OFF);
    float* scale = (float*)(ws + SC_OFF);
    float* shift = (float*)(ws + SH_OFF);
    float* bo2   = (float*)(ws + BO2_OFF);

    k_transpose<<<dim3(HW / 64, CH / 32, NB), 256, 0, stream>>>(x, xt);
    k_cvt_wi<<<dim3(CH * CH / 1024), 256, 0, stream>>>(Wi, Wib);
    hipMemsetAsync(ws + S1_OFF, 0, 2 * CH * sizeof(float), stream);
    k_gemm1<<<dim3(NPX / 64), 256, 0, stream>>>(Wib, bi, xt, s1);
    k_scale<<<dim3(1), 320, 0, stream>>>(s1, s2, gamma, beta, scale, shift);
    k_fold<<<dim3(CH), 64, 0, stream>>>(Wo, bo, scale, shift, Wos, bo2);
    k_gemm2_invol<<<dim3(HW / 64, NB), 256, 0, stream>>>(xt, Wos, bo2, x, out);
}